// Round 2
// baseline (3281.163 us; speedup 1.0000x reference)
//
#include <hip/hip_runtime.h>
#include <hip/hip_bf16.h>

#define BLOCK 704

__device__ __forceinline__ int clamp05(int v) { return v < 0 ? 0 : (v > 5 ? 5 : v); }

// Fully fused per-pair pipeline. One workgroup per (batch, relation) pair.
// LDS layout (static, 61824 B < 64 KB):
//   [0, 43264)      union { pooled1 chunk bf16[16*900] (28800 B) ; c2out bf16[32*676] (43264 B) }
//   [43264, 61696)  P: f32[128][36] 2D prefix sums of W1 kernels
//   [61696, 61824)  feat: f32[32]
__global__ __launch_bounds__(BLOCK) void vsgnet_fused_kernel(
    const float* __restrict__ bboxes,
    const int* __restrict__ obj_pairs,
    const int* __restrict__ fw_p,
    const int* __restrict__ fh_p,
    const float* __restrict__ W1,
    const float* __restrict__ b1,
    const float* __restrict__ W2,
    const float* __restrict__ b2,
    const float* __restrict__ Wl,
    const float* __restrict__ bl,
    float* __restrict__ out)
{
    __shared__ __align__(16) unsigned char smem[61824];
    __hip_bfloat16* pooled1 = reinterpret_cast<__hip_bfloat16*>(smem);
    __hip_bfloat16* c2out   = reinterpret_cast<__hip_bfloat16*>(smem);
    float* P    = reinterpret_cast<float*>(smem + 43264);
    float* feat = reinterpret_cast<float*>(smem + 61696);

    const int tid = threadIdx.x;
    const int t = blockIdx.x;       // pair index, t = b*64 + r
    const int bidx = t >> 6;        // R = 64

    // --- box coords (uniform; every thread computes redundantly) ---
    const int pa = obj_pairs[2*t];
    const int pb = obj_pairs[2*t + 1];
    const float* Ab = bboxes + (bidx*36 + pa)*4;
    const float* Bb = bboxes + (bidx*36 + pb)*4;
    const float sfx = (float)(64.0 / (double)fw_p[0]);
    const float sfy = (float)(64.0 / (double)fh_p[0]);
    const int x0a = (int)floorf(Ab[0]*sfx);
    const int y0a = (int)floorf(Ab[1]*sfy);
    const int x1a = (int)floorf(Ab[2]*sfx);
    const int y1a = (int)floorf(Ab[3]*sfy);
    const int x0b = (int)floorf(Bb[0]*sfx);
    const int y0b = (int)floorf(Bb[1]*sfy);
    const int x1b = (int)floorf(Bb[2]*sfx);
    const int y1b = (int)floorf(Bb[3]*sfy);

    // --- phase 0: 2D inclusive-exclusive prefix sums of each 5x5 W1 kernel ---
    if (tid < 128) {                      // 64 out-ch x 2 in-ch
        const float* w = W1 + tid*25;
        float p[6][6];
        #pragma unroll
        for (int r = 0; r < 6; ++r) p[r][0] = 0.f;
        #pragma unroll
        for (int c = 0; c < 6; ++c) p[0][c] = 0.f;
        #pragma unroll
        for (int r = 1; r < 6; ++r)
            #pragma unroll
            for (int c = 1; c < 6; ++c)
                p[r][c] = w[(r-1)*5 + (c-1)] + p[r-1][c] + p[r][c-1] - p[r-1][c-1];
        float* Pd = P + tid*36;
        #pragma unroll
        for (int r = 0; r < 6; ++r)
            #pragma unroll
            for (int c = 0; c < 6; ++c)
                Pd[r*6 + c] = p[r][c];
    }

    float acc[32];
    #pragma unroll
    for (int o = 0; o < 32; ++o) acc[o] = 0.f;

    const int ppi2 = tid / 26;            // conv2 output row (tid < 676)
    const int ppj2 = tid - ppi2*26;       // conv2 output col

    __syncthreads();

    // --- main loop over 4 chunks of 16 conv1 output channels ---
    for (int ch = 0; ch < 4; ++ch) {
        // phase 1: pooled conv1 for channels [16*ch, 16*ch+16) via rect-sum lookups
        for (int item = tid; item < 16*900; item += BLOCK) {
            const int lc = item / 900;
            const int p  = item - lc*900;
            const int c  = ch*16 + lc;
            const int pi = p / 30;
            const int pj = p - pi*30;
            const float* Pa  = P + (c*2 + 0)*36;
            const float* Pb2 = P + (c*2 + 1)*36;
            float mx = -3.0e38f;
            #pragma unroll
            for (int di = 0; di < 2; ++di) {
                const int i = pi*2 + di;
                const int r0a = clamp05(y0a - i), r1a = clamp05(y1a - i);
                const int r0b = clamp05(y0b - i), r1b = clamp05(y1b - i);
                #pragma unroll
                for (int dj = 0; dj < 2; ++dj) {
                    const int j = pj*2 + dj;
                    const int c0a = clamp05(x0a - j), c1a = clamp05(x1a - j);
                    const int c0b = clamp05(x0b - j), c1b = clamp05(x1b - j);
                    const float va = Pa[r1a*6+c1a] - Pa[r0a*6+c1a] - Pa[r1a*6+c0a] + Pa[r0a*6+c0a];
                    const float vb = Pb2[r1b*6+c1b] - Pb2[r0b*6+c1b] - Pb2[r1b*6+c0b] + Pb2[r0b*6+c0b];
                    mx = fmaxf(mx, va + vb);
                }
            }
            pooled1[item] = __float2bfloat16(mx + b1[c]);
        }
        __syncthreads();

        // phase 2: conv2 partial accumulation (one output pixel per thread)
        if (tid < 676) {
            for (int lc = 0; lc < 16; ++lc) {
                const __hip_bfloat16* src = pooled1 + lc*900 + ppi2*30 + ppj2;
                const float* wbase = W2 + (ch*16 + lc)*25;   // + oc*1600 + di*5 + dj
                #pragma unroll
                for (int di = 0; di < 5; ++di) {
                    const float w0 = __bfloat162float(src[di*30 + 0]);
                    const float w1v = __bfloat162float(src[di*30 + 1]);
                    const float w2v = __bfloat162float(src[di*30 + 2]);
                    const float w3 = __bfloat162float(src[di*30 + 3]);
                    const float w4 = __bfloat162float(src[di*30 + 4]);
                    #pragma unroll
                    for (int oc = 0; oc < 32; ++oc) {
                        const float* wv = wbase + oc*1600 + di*5;
                        float s = acc[oc];
                        s = fmaf(w0, wv[0], s);
                        s = fmaf(w1v, wv[1], s);
                        s = fmaf(w2v, wv[2], s);
                        s = fmaf(w3, wv[3], s);
                        s = fmaf(w4, wv[4], s);
                        acc[oc] = s;
                    }
                }
            }
        }
        __syncthreads();   // protects pooled1 before next chunk overwrites
    }

    // --- phase 3: bias, stage conv2 output (bf16, reuses LDS), pool2 + mean ---
    if (tid < 32) feat[tid] = 0.f;
    if (tid < 676) {
        #pragma unroll
        for (int oc = 0; oc < 32; ++oc)
            c2out[oc*676 + tid] = __float2bfloat16(acc[oc] + b2[oc]);
    }
    __syncthreads();

    for (int item = tid; item < 32*169; item += BLOCK) {
        const int oc   = item / 169;
        const int cell = item - oc*169;
        const int ci = cell / 13;
        const int cj = cell - ci*13;
        const __hip_bfloat16* q = c2out + oc*676 + (ci*2)*26 + cj*2;
        const float v0 = __bfloat162float(q[0]);
        const float v1 = __bfloat162float(q[1]);
        const float v2 = __bfloat162float(q[26]);
        const float v3 = __bfloat162float(q[27]);
        const float mx = fmaxf(fmaxf(v0, v1), fmaxf(v2, v3));
        atomicAdd(&feat[oc], mx * (1.0f/169.0f));
    }
    __syncthreads();

    // --- phase 4: linear 32 -> 512 + ReLU ---
    if (tid < 512) {
        float s = bl[tid];
        #pragma unroll
        for (int ic = 0; ic < 32; ++ic)
            s = fmaf(feat[ic], Wl[ic*512 + tid], s);
        out[(size_t)t*512 + tid] = fmaxf(s, 0.f);
    }
}

extern "C" void kernel_launch(void* const* d_in, const int* in_sizes, int n_in,
                              void* d_out, int out_size, void* d_ws, size_t ws_size,
                              hipStream_t stream) {
    const float* bboxes    = (const float*)d_in[0];
    const int*   obj_pairs = (const int*)d_in[1];
    // d_in[2] = num_rels (reference ignores it; all batches use full R)
    const int*   fw        = (const int*)d_in[3];
    const int*   fh        = (const int*)d_in[4];
    const float* W1        = (const float*)d_in[5];
    const float* b1        = (const float*)d_in[6];
    const float* W2        = (const float*)d_in[7];
    const float* b2        = (const float*)d_in[8];
    const float* Wl        = (const float*)d_in[9];
    const float* bl        = (const float*)d_in[10];
    float* out = (float*)d_out;

    vsgnet_fused_kernel<<<dim3(1024), dim3(BLOCK), 0, stream>>>(
        bboxes, obj_pairs, fw, fh, W1, b1, W2, b2, Wl, bl, out);
}

// Round 3
// 356.472 us; speedup vs baseline: 9.2046x; 9.2046x over previous
//
#include <hip/hip_runtime.h>
#include <hip/hip_bf16.h>

#define BLOCK 1024

typedef __attribute__((ext_vector_type(8))) short short8;   // 8 bf16 (4 VGPR)
typedef __attribute__((ext_vector_type(4))) float floatx4;  // MFMA C/D

// LDS layout (dynamic, 140160 B):
//   [0, 18432)        P:    f32 [2 box][36 corner][64 ch]
//   [18432, 82432)    w2s:  bf16 [25 tap][32 oc][40 ic-pad]   (64000 B)
//   [82432, 140032)   pool1 bf16 [900 pos][32 ic]  (57600 B); reused as c2out bf16[676][32]
//   [140032, 140160)  feat: f32[32]
#define SMEM_P     0
#define SMEM_W2    18432
#define SMEM_POOL  82432
#define SMEM_FEAT  140032
#define SMEM_TOTAL 140160

__device__ __forceinline__ int clamp05(int v) { return v < 0 ? 0 : (v > 5 ? 5 : v); }

__global__ __launch_bounds__(BLOCK) void vsgnet_mfma_kernel(
    const float* __restrict__ bboxes,
    const int* __restrict__ obj_pairs,
    const int* __restrict__ fw_p,
    const int* __restrict__ fh_p,
    const float* __restrict__ W1,
    const float* __restrict__ b1,
    const float* __restrict__ W2,
    const float* __restrict__ b2,
    const float* __restrict__ Wl,
    const float* __restrict__ bl,
    float* __restrict__ out)
{
    extern __shared__ __align__(16) char smem[];
    float* Pf = (float*)(smem + SMEM_P);
    __hip_bfloat16* w2s   = (__hip_bfloat16*)(smem + SMEM_W2);
    __hip_bfloat16* pool1 = (__hip_bfloat16*)(smem + SMEM_POOL);
    __hip_bfloat16* c2out = pool1;
    float* feat = (float*)(smem + SMEM_FEAT);

    const int tid = threadIdx.x;
    const int t = blockIdx.x;       // pair index
    const int bidx = t >> 6;        // R = 64

    // --- box coords (uniform per block) ---
    const int pa = obj_pairs[2*t];
    const int pb = obj_pairs[2*t + 1];
    const float* Ab = bboxes + (bidx*36 + pa)*4;
    const float* Bb = bboxes + (bidx*36 + pb)*4;
    const float sfx = (float)(64.0 / (double)fw_p[0]);
    const float sfy = (float)(64.0 / (double)fh_p[0]);
    const int x0a = (int)floorf(Ab[0]*sfx);
    const int y0a = (int)floorf(Ab[1]*sfy);
    const int x1a = (int)floorf(Ab[2]*sfx);
    const int y1a = (int)floorf(Ab[3]*sfy);
    const int x0b = (int)floorf(Bb[0]*sfx);
    const int y0b = (int)floorf(Bb[1]*sfy);
    const int x1b = (int)floorf(Bb[2]*sfx);
    const int y1b = (int)floorf(Bb[3]*sfy);

    // --- phase 0: prefix sums of W1 kernels -> P[box][corner][ch] ---
    if (tid < 128) {
        const int c = tid & 63;
        const int box = tid >> 6;
        const float* w = W1 + (c*2 + box)*25;
        float p[6][6];
        #pragma unroll
        for (int r = 0; r < 6; ++r) p[r][0] = 0.f;
        #pragma unroll
        for (int cc = 0; cc < 6; ++cc) p[0][cc] = 0.f;
        #pragma unroll
        for (int r = 1; r < 6; ++r)
            #pragma unroll
            for (int cc = 1; cc < 6; ++cc)
                p[r][cc] = w[(r-1)*5 + (cc-1)] + p[r-1][cc] + p[r][cc-1] - p[r-1][cc-1];
        float* Pd = Pf + box*2304;   // 36*64
        #pragma unroll
        for (int r = 0; r < 6; ++r)
            #pragma unroll
            for (int cc = 0; cc < 6; ++cc)
                Pd[(r*6 + cc)*64 + c] = p[r][cc];
    }

    const int lane = tid & 63;
    const int wid  = tid >> 6;      // 16 waves
    const int kg   = lane >> 4;     // k-group (MFMA)
    const int lr   = lane & 15;     // row/col within fragment

    // per-wave M-tile bases for A gathers (43 tiles of 16 rows, padded to 688)
    floatx4 acc[3][2];
    #pragma unroll
    for (int s = 0; s < 3; ++s)
        #pragma unroll
        for (int n = 0; n < 2; ++n)
            acc[s][n] = (floatx4){0.f, 0.f, 0.f, 0.f};
    int abase[3];
    #pragma unroll
    for (int s = 0; s < 3; ++s) {
        const int mt = wid + 16*s;
        int m = mt*16 + lr; if (m > 675) m = 675;   // clamp pad rows (discarded later)
        const int pi = m / 26;
        const int pj = m - pi*26;
        abase[s] = SMEM_POOL + ((pi*30 + pj)*32 + kg*8)*2;
    }
    const int bbase = SMEM_W2 + (lr*40 + kg*8)*2;

    // phase-1 lane roles: lane = (cell parity, ic-in-chunk)
    const int ch_l = lane & 31;
    const int half = lane >> 5;

    __syncthreads();   // P ready

    for (int ch = 0; ch < 2; ++ch) {
        const int icb = ch*32;

        // --- W2 staging: w2s[tap][oc][ic] = bf16(W2[oc][icb+ic][tap]) ---
        for (int idx = tid; idx < 25600; idx += BLOCK) {
            const int tap = idx >> 10;
            const int rem = idx & 1023;
            const int oc  = rem >> 5;
            const int ic  = rem & 31;
            w2s[tap*1280 + oc*40 + ic] =
                __float2bfloat16(W2[oc*1600 + (icb + ic)*25 + tap]);
        }

        // --- phase 1: pooled conv1 for 32 channels -> pool1[pos][ic] ---
        const float b1v = b1[icb + ch_l];
        const float* Pc = Pf + icb + ch_l;   // channel-indexed base
        for (int base = wid; base < 450; base += 16) {
            const int cell = base*2 + half;
            const int pi = cell / 30;
            const int pj = cell - pi*30;
            int r0a[2], r1a[2], r0b[2], r1b[2], c0a[2], c1a[2], c0b[2], c1b[2];
            #pragma unroll
            for (int d = 0; d < 2; ++d) {
                const int i = 2*pi + d;
                r0a[d] = clamp05(y0a - i); r1a[d] = clamp05(y1a - i);
                r0b[d] = clamp05(y0b - i); r1b[d] = clamp05(y1b - i);
                const int j = 2*pj + d;
                c0a[d] = clamp05(x0a - j); c1a[d] = clamp05(x1a - j);
                c0b[d] = clamp05(x0b - j); c1b[d] = clamp05(x1b - j);
            }
            float mx = -3.0e38f;
            #pragma unroll
            for (int di = 0; di < 2; ++di) {
                #pragma unroll
                for (int dj = 0; dj < 2; ++dj) {
                    const float va = Pc[(r1a[di]*6 + c1a[dj])*64] - Pc[(r0a[di]*6 + c1a[dj])*64]
                                   - Pc[(r1a[di]*6 + c0a[dj])*64] + Pc[(r0a[di]*6 + c0a[dj])*64];
                    const float vb = Pc[2304 + (r1b[di]*6 + c1b[dj])*64] - Pc[2304 + (r0b[di]*6 + c1b[dj])*64]
                                   - Pc[2304 + (r1b[di]*6 + c0b[dj])*64] + Pc[2304 + (r0b[di]*6 + c0b[dj])*64];
                    mx = fmaxf(mx, va + vb);
                }
            }
            pool1[cell*32 + ch_l] = __float2bfloat16(mx + b1v);
        }
        __syncthreads();   // pool1 + w2s ready

        // --- phase 2: implicit-GEMM MFMA, K-chunk = 32 ic x 25 taps ---
        #pragma unroll
        for (int tap = 0; tap < 25; ++tap) {
            const int toffA = ((tap/5)*30 + (tap%5))*64;   // bytes
            const int toffB = tap*2560;                    // bytes
            const short8 bf0 = *(const short8*)(smem + bbase + toffB);
            const short8 bf1 = *(const short8*)(smem + bbase + toffB + 1280);
            #pragma unroll
            for (int s = 0; s < 3; ++s) {
                if (wid + 16*s < 43) {
                    const short8 af = *(const short8*)(smem + abase[s] + toffA);
                    acc[s][0] = __builtin_amdgcn_mfma_f32_16x16x32_bf16(af, bf0, acc[s][0], 0, 0, 0);
                    acc[s][1] = __builtin_amdgcn_mfma_f32_16x16x32_bf16(af, bf1, acc[s][1], 0, 0, 0);
                }
            }
        }
        __syncthreads();   // drain reads before next chunk overwrites LDS
    }

    // --- epilogue: C -> bf16 c2out[m][oc] (C layout: col=lane&15, row=(lane>>4)*4+reg) ---
    if (tid < 32) feat[tid] = 0.f;
    const float b2v0 = b2[lr];
    const float b2v1 = b2[16 + lr];
    #pragma unroll
    for (int s = 0; s < 3; ++s) {
        const int mt = wid + 16*s;
        if (mt < 43) {
            #pragma unroll
            for (int r = 0; r < 4; ++r) {
                const int m = mt*16 + kg*4 + r;
                if (m < 676) {
                    c2out[m*32 + lr]      = __float2bfloat16(acc[s][0][r] + b2v0);
                    c2out[m*32 + 16 + lr] = __float2bfloat16(acc[s][1][r] + b2v1);
                }
            }
        }
    }
    __syncthreads();

    // --- pool2 2x2 + mean(13x13): pre-reduced per-thread, then one atomic ---
    {
        const int oc  = tid & 31;
        const int grp = tid >> 5;
        float sum = 0.f;
        for (int cell = grp; cell < 169; cell += 32) {
            const int ci = cell / 13;
            const int cj = cell - ci*13;
            const __hip_bfloat16* q = c2out + ((ci*2)*26 + cj*2)*32 + oc;
            const float v0 = __bfloat162float(q[0]);
            const float v1 = __bfloat162float(q[32]);
            const float v2 = __bfloat162float(q[26*32]);
            const float v3 = __bfloat162float(q[27*32]);
            sum += fmaxf(fmaxf(v0, v1), fmaxf(v2, v3));
        }
        atomicAdd(&feat[oc], sum * (1.0f/169.0f));
    }
    __syncthreads();

    // --- linear 32 -> 512 + ReLU ---
    if (tid < 512) {
        float s = bl[tid];
        #pragma unroll
        for (int ic = 0; ic < 32; ++ic)
            s = fmaf(feat[ic], Wl[ic*512 + tid], s);
        out[(size_t)t*512 + tid] = fmaxf(s, 0.f);
    }
}

extern "C" void kernel_launch(void* const* d_in, const int* in_sizes, int n_in,
                              void* d_out, int out_size, void* d_ws, size_t ws_size,
                              hipStream_t stream) {
    const float* bboxes    = (const float*)d_in[0];
    const int*   obj_pairs = (const int*)d_in[1];
    // d_in[2] = num_rels (reference ignores it)
    const int*   fw        = (const int*)d_in[3];
    const int*   fh        = (const int*)d_in[4];
    const float* W1        = (const float*)d_in[5];
    const float* b1        = (const float*)d_in[6];
    const float* W2        = (const float*)d_in[7];
    const float* b2        = (const float*)d_in[8];
    const float* Wl        = (const float*)d_in[9];
    const float* bl        = (const float*)d_in[10];
    float* out = (float*)d_out;

    hipFuncSetAttribute((const void*)vsgnet_mfma_kernel,
                        hipFuncAttributeMaxDynamicSharedMemorySize, SMEM_TOTAL);
    vsgnet_mfma_kernel<<<dim3(1024), dim3(BLOCK), SMEM_TOTAL, stream>>>(
        bboxes, obj_pairs, fw, fh, W1, b1, W2, b2, Wl, bl, out);
}

// Round 4
// 251.393 us; speedup vs baseline: 13.0519x; 1.4180x over previous
//
#include <hip/hip_runtime.h>
#include <hip/hip_bf16.h>

#define BLOCK 1024
#define NREG  21          // max distinct row (col) regimes: 20 breakpoints + 1
#define NCOMBO (NREG*NREG)

typedef __attribute__((ext_vector_type(8))) short short8;   // 8 bf16
typedef __attribute__((ext_vector_type(4))) float floatx4;  // MFMA C/D

// LDS (dynamic, 141664 B):
//  [0,18432)        P: f32[2 box][36 corner][64 ch]
//  [18432,76032)    w2s bf16[25][32 oc][36 icpad] (57600) ; V bf16[441][32] (28224) overlays
//  [76032,140832)   pool1 bf16[900][36 pad] (64800) ; Q f32[2][21][6][32] (32256) overlays ; c2out bf16[676][36]
//  [140832,140960)  feat f32[32]
//  [140960,141608)  tables: band_row[60], band_col[60], rep_row[21], rep_col[21] (int)
#define SMEM_P     0
#define SMEM_W2    18432
#define SMEM_POOL  76032
#define SMEM_FEAT  140832
#define SMEM_TAB   140960
#define SMEM_TOTAL 141664

__device__ __forceinline__ int clamp05(int v) { return v < 0 ? 0 : (v > 5 ? 5 : v); }

// # of regime breakpoints <= i  (value changes of clamp05(e-i) occur at i in [e-4, e])
__device__ __forceinline__ int band_id(int i, int e0, int e1, int e2, int e3) {
    int c = 0;
    #pragma unroll
    for (int k = 0; k < 5; ++k) {
        const int b0 = e0 - k, b1 = e1 - k, b2 = e2 - k, b3 = e3 - k;
        c += (b0 >= 1 && i >= b0);
        c += (b1 >= 1 && i >= b1);
        c += (b2 >= 1 && i >= b2);
        c += (b3 >= 1 && i >= b3);
    }
    return c;
}

__global__ __launch_bounds__(BLOCK) void vsgnet_mfma_kernel(
    const float* __restrict__ bboxes,
    const int* __restrict__ obj_pairs,
    const int* __restrict__ fw_p,
    const int* __restrict__ fh_p,
    const float* __restrict__ W1,
    const float* __restrict__ b1,
    const float* __restrict__ W2,
    const float* __restrict__ b2,
    const float* __restrict__ Wl,
    const float* __restrict__ bl,
    float* __restrict__ out)
{
    extern __shared__ __align__(16) char smem[];
    float* Pf = (float*)(smem + SMEM_P);
    __hip_bfloat16* w2s   = (__hip_bfloat16*)(smem + SMEM_W2);
    __hip_bfloat16* Vb    = (__hip_bfloat16*)(smem + SMEM_W2);   // overlay
    unsigned int*   V32   = (unsigned int*)(smem + SMEM_W2);
    __hip_bfloat16* pool1 = (__hip_bfloat16*)(smem + SMEM_POOL);
    float*          Qf    = (float*)(smem + SMEM_POOL);          // overlay
    __hip_bfloat16* c2out = pool1;
    float* feat = (float*)(smem + SMEM_FEAT);
    int* tab = (int*)(smem + SMEM_TAB);
    int* band_row = tab;         // [60]
    int* band_col = tab + 60;    // [60]
    int* rep_row  = tab + 120;   // [21]
    int* rep_col  = tab + 141;   // [21]

    const int tid = threadIdx.x;
    const int t = blockIdx.x;
    const int bidx = t >> 6;

    // --- uniform box coords ---
    const int pa = obj_pairs[2*t];
    const int pb = obj_pairs[2*t + 1];
    const float* Ab = bboxes + (bidx*36 + pa)*4;
    const float* Bb = bboxes + (bidx*36 + pb)*4;
    const float sfx = (float)(64.0 / (double)fw_p[0]);
    const float sfy = (float)(64.0 / (double)fh_p[0]);
    const int x0a = (int)floorf(Ab[0]*sfx);
    const int y0a = (int)floorf(Ab[1]*sfy);
    const int x1a = (int)floorf(Ab[2]*sfx);
    const int y1a = (int)floorf(Ab[3]*sfy);
    const int x0b = (int)floorf(Bb[0]*sfx);
    const int y0b = (int)floorf(Bb[1]*sfy);
    const int x1b = (int)floorf(Bb[2]*sfx);
    const int y1b = (int)floorf(Bb[3]*sfy);

    // --- init rep tables + W1 prefix sums ---
    if (tid < 42) tab[120 + tid] = -1;
    if (tid < 128) {
        const int c = tid & 63;
        const int box = tid >> 6;
        const float* w = W1 + (c*2 + box)*25;
        float p[6][6];
        #pragma unroll
        for (int r = 0; r < 6; ++r) p[r][0] = 0.f;
        #pragma unroll
        for (int cc = 0; cc < 6; ++cc) p[0][cc] = 0.f;
        #pragma unroll
        for (int r = 1; r < 6; ++r)
            #pragma unroll
            for (int cc = 1; cc < 6; ++cc)
                p[r][cc] = w[(r-1)*5 + (cc-1)] + p[r-1][cc] + p[r][cc-1] - p[r-1][cc-1];
        float* Pd = Pf + box*2304;
        #pragma unroll
        for (int r = 0; r < 6; ++r)
            #pragma unroll
            for (int cc = 0; cc < 6; ++cc)
                Pd[(r*6 + cc)*64 + c] = p[r][cc];
    }
    __syncthreads();

    // --- band tables (rows 0..59, cols 0..59); rep = any member (race ok) ---
    if (tid < 60) {
        const int bnd = band_id(tid, y0a, y1a, y0b, y1b);
        band_row[tid] = bnd;
        rep_row[bnd] = tid;
    } else if (tid >= 64 && tid < 124) {
        const int j = tid - 64;
        const int bnd = band_id(j, x0a, x1a, x0b, x1b);
        band_col[j] = bnd;
        rep_col[bnd] = j;
    }

    const int lane = tid & 63;
    const int wid  = tid >> 6;
    const int kg   = lane >> 4;
    const int lr   = lane & 15;

    floatx4 acc[3][2];
    #pragma unroll
    for (int s = 0; s < 3; ++s)
        #pragma unroll
        for (int n = 0; n < 2; ++n)
            acc[s][n] = (floatx4){0.f, 0.f, 0.f, 0.f};
    int abase[3];
    #pragma unroll
    for (int s = 0; s < 3; ++s) {
        const int mt = wid + 16*s;
        int m = mt*16 + lr; if (m > 675) m = 675;
        const int pi = m / 26;
        const int pj = m - pi*26;
        abase[s] = SMEM_POOL + ((pi*30 + pj)*36 + kg*8)*2;
    }
    const int bbase = SMEM_W2 + (lr*36 + kg*8)*2;

    const int chl = tid & 31;             // channel-in-chunk for build phases
    const int ocl = tid >> 5;             // 0..31
    const float b1r[2] = { b1[chl], b1[32 + chl] };

    __syncthreads();   // P + tables ready

    for (int ch = 0; ch < 2; ++ch) {
        const int icb = ch*32;

        // issue W2 loads early (contiguous per thread: addr+p), consumed after pool-build
        float w2reg[25];
        {
            const float* src = W2 + ocl*1600 + (icb + chl)*25;
            #pragma unroll
            for (int p = 0; p < 25; ++p) w2reg[p] = src[p];
        }

        // --- Q-build: Q[box][rb][c][ch] = P[box][r1*6+c][ch] - P[box][r0*6+c][ch] ---
        for (int idx = tid; idx < 2*NREG*6*32; idx += BLOCK) {
            const int c = (idx >> 5) % 6;
            const int g = (idx >> 5) / 6;      // box*21 + rb
            const int box = g / NREG;
            const int rb  = g - box*NREG;
            const int i = rep_row[rb];
            if (i >= 0) {
                int r0, r1;
                if (box == 0) { r0 = clamp05(y0a - i); r1 = clamp05(y1a - i); }
                else          { r0 = clamp05(y0b - i); r1 = clamp05(y1b - i); }
                const float* Pb_ = Pf + box*2304 + icb + chl;
                Qf[idx] = Pb_[(r1*6 + c)*64] - Pb_[(r0*6 + c)*64];
            }
        }
        __syncthreads();

        // --- V-build: V[rb*21+cb][ch] = bf16(Qa[c1a]-Qa[c0a]+Qb[c1b]-Qb[c0b]+b1) ---
        for (int idx = tid; idx < NCOMBO*32; idx += BLOCK) {
            const int combo = idx >> 5;
            const int rb = combo / NREG;
            const int cb = combo - rb*NREG;
            const int j  = rep_col[cb];
            if (j >= 0 && rep_row[rb] >= 0) {
                const int c0a = clamp05(x0a - j), c1a = clamp05(x1a - j);
                const int c0b = clamp05(x0b - j), c1b = clamp05(x1b - j);
                const float* Qa = Qf + (rb*6)*32 + chl;
                const float* Qb = Qf + ((NREG + rb)*6)*32 + chl;
                const float v = Qa[c1a*32] - Qa[c0a*32] + Qb[c1b*32] - Qb[c0b*32] + b1r[ch];
                Vb[combo*32 + chl] = __float2bfloat16(v);
            }
        }
        __syncthreads();

        // --- pool-build: pool1[cell][ch] = max over <=4 band combos (packed bf16x2) ---
        for (int idx = tid; idx < 900*16; idx += BLOCK) {
            const int chp  = idx & 15;
            const int cell = idx >> 4;
            const int pi = cell / 30;
            const int pj = cell - pi*30;
            const int rb0 = band_row[2*pi], rb1 = band_row[2*pi + 1];
            const int cb0 = band_col[2*pj], cb1 = band_col[2*pj + 1];
            const unsigned int u0 = V32[(rb0*NREG + cb0)*16 + chp];
            const unsigned int u1 = V32[(rb0*NREG + cb1)*16 + chp];
            const unsigned int u2 = V32[(rb1*NREG + cb0)*16 + chp];
            const unsigned int u3 = V32[(rb1*NREG + cb1)*16 + chp];
            const float a0 = __uint_as_float(u0 << 16), h0 = __uint_as_float(u0 & 0xffff0000u);
            const float a1 = __uint_as_float(u1 << 16), h1 = __uint_as_float(u1 & 0xffff0000u);
            const float a2 = __uint_as_float(u2 << 16), h2 = __uint_as_float(u2 & 0xffff0000u);
            const float a3 = __uint_as_float(u3 << 16), h3 = __uint_as_float(u3 & 0xffff0000u);
            const float ml = fmaxf(fmaxf(a0, a1), fmaxf(a2, a3));
            const float mh = fmaxf(fmaxf(h0, h1), fmaxf(h2, h3));
            const unsigned int packed = (__float_as_uint(ml) >> 16) | (__float_as_uint(mh) & 0xffff0000u);
            *(unsigned int*)(smem + SMEM_POOL + (cell*36 + 2*chp)*2) = packed;
        }
        __syncthreads();

        // --- w2s write: bf16 [tap][oc][icpad36] (V region no longer needed) ---
        #pragma unroll
        for (int p = 0; p < 25; ++p)
            w2s[p*1152 + ocl*36 + chl] = __float2bfloat16(w2reg[p]);
        __syncthreads();

        // --- MFMA: K-chunk = 32 ic x 25 taps ---
        #pragma unroll
        for (int tap = 0; tap < 25; ++tap) {
            const int toffA = ((tap/5)*30 + (tap%5))*72;
            const int toffB = tap*2304;
            const short8 bf0 = *(const short8*)(smem + bbase + toffB);
            const short8 bf1 = *(const short8*)(smem + bbase + toffB + 1152);
            #pragma unroll
            for (int s = 0; s < 3; ++s) {
                if (wid + 16*s < 43) {
                    const short8 af = *(const short8*)(smem + abase[s] + toffA);
                    acc[s][0] = __builtin_amdgcn_mfma_f32_16x16x32_bf16(af, bf0, acc[s][0], 0, 0, 0);
                    acc[s][1] = __builtin_amdgcn_mfma_f32_16x16x32_bf16(af, bf1, acc[s][1], 0, 0, 0);
                }
            }
        }
        __syncthreads();
    }

    // --- epilogue: C (col=lane&15, row=(lane>>4)*4+reg) -> c2out[m][oc], stride 36 ---
    if (tid < 32) feat[tid] = 0.f;
    const float b2v0 = b2[lr];
    const float b2v1 = b2[16 + lr];
    #pragma unroll
    for (int s = 0; s < 3; ++s) {
        const int mt = wid + 16*s;
        if (mt < 43) {
            #pragma unroll
            for (int r = 0; r < 4; ++r) {
                const int m = mt*16 + kg*4 + r;
                if (m < 676) {
                    c2out[m*36 + lr]      = __float2bfloat16(acc[s][0][r] + b2v0);
                    c2out[m*36 + 16 + lr] = __float2bfloat16(acc[s][1][r] + b2v1);
                }
            }
        }
    }
    __syncthreads();

    // --- pool2 2x2 + mean(13x13) ---
    {
        const int oc  = tid & 31;
        const int grp = tid >> 5;
        float sum = 0.f;
        for (int cell = grp; cell < 169; cell += 32) {
            const int ci = cell / 13;
            const int cj = cell - ci*13;
            const __hip_bfloat16* q = c2out + ((ci*2)*26 + cj*2)*36 + oc;
            const float v0 = __bfloat162float(q[0]);
            const float v1 = __bfloat162float(q[36]);
            const float v2 = __bfloat162float(q[936]);
            const float v3 = __bfloat162float(q[972]);
            sum += fmaxf(fmaxf(v0, v1), fmaxf(v2, v3));
        }
        atomicAdd(&feat[oc], sum * (1.0f/169.0f));
    }
    __syncthreads();

    // --- linear 32 -> 512 + ReLU ---
    if (tid < 512) {
        float s = bl[tid];
        #pragma unroll
        for (int ic = 0; ic < 32; ++ic)
            s = fmaf(feat[ic], Wl[ic*512 + tid], s);
        out[(size_t)t*512 + tid] = fmaxf(s, 0.f);
    }
}

extern "C" void kernel_launch(void* const* d_in, const int* in_sizes, int n_in,
                              void* d_out, int out_size, void* d_ws, size_t ws_size,
                              hipStream_t stream) {
    const float* bboxes    = (const float*)d_in[0];
    const int*   obj_pairs = (const int*)d_in[1];
    const int*   fw        = (const int*)d_in[3];
    const int*   fh        = (const int*)d_in[4];
    const float* W1        = (const float*)d_in[5];
    const float* b1        = (const float*)d_in[6];
    const float* W2        = (const float*)d_in[7];
    const float* b2        = (const float*)d_in[8];
    const float* Wl        = (const float*)d_in[9];
    const float* bl        = (const float*)d_in[10];
    float* out = (float*)d_out;

    hipFuncSetAttribute((const void*)vsgnet_mfma_kernel,
                        hipFuncAttributeMaxDynamicSharedMemorySize, SMEM_TOTAL);
    vsgnet_mfma_kernel<<<dim3(1024), dim3(BLOCK), SMEM_TOTAL, stream>>>(
        bboxes, obj_pairs, fw, fh, W1, b1, W2, b2, Wl, bl, out);
}

// Round 5
// 200.320 us; speedup vs baseline: 16.3796x; 1.2550x over previous
//
#include <hip/hip_runtime.h>
#include <hip/hip_bf16.h>

#define BLOCK 1024
#define NREG  21
#define NCOMBO (NREG*NREG)

typedef __attribute__((ext_vector_type(8))) short short8;       // 8 bf16
typedef __attribute__((ext_vector_type(4))) float floatx4;
typedef __attribute__((ext_vector_type(4))) unsigned int uint4v;

// LDS map (bytes):
//  [0,18432)        P f32 [2][36][64]
//  [18432,69632)    R: Q f32 [252][36] (Q dead after V-build) then w2s bf16 [25][32][32]
//  [69632,97856)    V bf16 [441][32]
//  [97856,155456)   pool1 bf16 [900][32] ; c2out bf16 [676][32] overlay
//  [155456,155584)  feat f32[32]
//  [155584,156232)  tables: band_row[60], band_col[60], rep_row[21], rep_col[21]
#define SMEM_P     0
#define SMEM_R     18432
#define SMEM_V     69632
#define SMEM_POOL  97856
#define SMEM_FEAT  155456
#define SMEM_TAB   155584
#define SMEM_TOTAL 156256

__device__ __forceinline__ int clamp05(int v) { return v < 0 ? 0 : (v > 5 ? 5 : v); }

__device__ __forceinline__ int band_id(int i, int e0, int e1, int e2, int e3) {
    int c = 0;
    #pragma unroll
    for (int k = 0; k < 5; ++k) {
        const int b0 = e0 - k, b1 = e1 - k, b2 = e2 - k, b3 = e3 - k;
        c += (b0 >= 1 && i >= b0);
        c += (b1 >= 1 && i >= b1);
        c += (b2 >= 1 && i >= b2);
        c += (b3 >= 1 && i >= b3);
    }
    return c;
}

__global__ __launch_bounds__(BLOCK) void vsgnet_mfma_kernel(
    const float* __restrict__ bboxes,
    const int* __restrict__ obj_pairs,
    const int* __restrict__ fw_p,
    const int* __restrict__ fh_p,
    const float* __restrict__ W1,
    const float* __restrict__ b1,
    const float* __restrict__ W2,
    const float* __restrict__ b2,
    const float* __restrict__ Wl,
    const float* __restrict__ bl,
    float* __restrict__ out)
{
    extern __shared__ __align__(16) char smem[];
    float* Pf = (float*)(smem + SMEM_P);
    float* Qf = (float*)(smem + SMEM_R);            // [252][36] f32
    __hip_bfloat16* w2s = (__hip_bfloat16*)(smem + SMEM_R);   // overlay after V-build
    float* feat = (float*)(smem + SMEM_FEAT);
    int* tab = (int*)(smem + SMEM_TAB);
    int* band_row = tab;
    int* band_col = tab + 60;
    int* rep_row  = tab + 120;
    int* rep_col  = tab + 141;

    const int tid = threadIdx.x;
    const int t = blockIdx.x;
    const int bidx = t >> 6;

    // --- uniform box coords ---
    const int pa = obj_pairs[2*t];
    const int pb = obj_pairs[2*t + 1];
    const float* Ab = bboxes + (bidx*36 + pa)*4;
    const float* Bb = bboxes + (bidx*36 + pb)*4;
    const float sfx = (float)(64.0 / (double)fw_p[0]);
    const float sfy = (float)(64.0 / (double)fh_p[0]);
    const int x0a = (int)floorf(Ab[0]*sfx);
    const int y0a = (int)floorf(Ab[1]*sfy);
    const int x1a = (int)floorf(Ab[2]*sfx);
    const int y1a = (int)floorf(Ab[3]*sfy);
    const int x0b = (int)floorf(Bb[0]*sfx);
    const int y0b = (int)floorf(Bb[1]*sfy);
    const int x1b = (int)floorf(Bb[2]*sfx);
    const int y1b = (int)floorf(Bb[3]*sfy);

    // --- P build + rep init ---
    if (tid < 42) tab[120 + tid] = -1;
    if (tid < 128) {
        const int c = tid & 63;
        const int box = tid >> 6;
        const float* w = W1 + (c*2 + box)*25;
        float p[6][6];
        #pragma unroll
        for (int r = 0; r < 6; ++r) p[r][0] = 0.f;
        #pragma unroll
        for (int cc = 0; cc < 6; ++cc) p[0][cc] = 0.f;
        #pragma unroll
        for (int r = 1; r < 6; ++r)
            #pragma unroll
            for (int cc = 1; cc < 6; ++cc)
                p[r][cc] = w[(r-1)*5 + (cc-1)] + p[r-1][cc] + p[r][cc-1] - p[r-1][cc-1];
        float* Pd = Pf + box*2304;
        #pragma unroll
        for (int r = 0; r < 6; ++r)
            #pragma unroll
            for (int cc = 0; cc < 6; ++cc)
                Pd[(r*6 + cc)*64 + c] = p[r][cc];
    }
    __syncthreads();

    // --- band tables ---
    if (tid < 60) {
        const int bnd = band_id(tid, y0a, y1a, y0b, y1b);
        band_row[tid] = bnd;
        rep_row[bnd] = tid;
    } else if (tid >= 64 && tid < 124) {
        const int j = tid - 64;
        const int bnd = band_id(j, x0a, x1a, x0b, x1b);
        band_col[j] = bnd;
        rep_col[bnd] = j;
    }

    const int lane = tid & 63;
    const int wid  = tid >> 6;
    const int kg   = lane >> 4;
    const int lr   = lane & 15;

    // MFMA geometry: 8 waves x 6 M-tiles (43 tiles of 16 rows), N=32 (2 frags)
    floatx4 acc[6][2];
    #pragma unroll
    for (int s = 0; s < 6; ++s) {
        acc[s][0] = (floatx4){0.f,0.f,0.f,0.f};
        acc[s][1] = (floatx4){0.f,0.f,0.f,0.f};
    }
    int abase[6];
    #pragma unroll
    for (int s = 0; s < 6; ++s) {
        const int mt = (wid & 7) + 8*s;
        int m = mt*16 + lr; if (m > 675) m = 675;
        const int pi = m / 26;
        const int pj = m - pi*26;
        abase[s] = SMEM_POOL + ((pi*30 + pj)*32 + kg*8)*2;
    }
    const int bbase = SMEM_R + (lr*32 + kg*8)*2;

    const int ocl = tid >> 5;       // 0..31
    const int chl = tid & 31;       // 0..31

    __syncthreads();   // P + tables ready

    for (int ch = 0; ch < 2; ++ch) {
        const int icb = ch*32;

        // W2 preload (global, hidden under build phases); thread (ocl, chl)
        float w2reg[25];
        {
            const float* src = W2 + ocl*1600 + (icb + chl)*25;
            #pragma unroll
            for (int p = 0; p < 25; ++p) w2reg[p] = src[p];
        }

        // --- Q-build: Q[k=(box,rb,c)][lc 0..31] = P[r1]-P[r0], 8ch per item ---
        if (tid < 1008) {
            const int g = tid & 3;
            const int k = tid >> 2;          // 0..251
            const int box = (k >= 126);
            const int kk  = k - box*126;
            const int rb  = kk / 6;
            const int c   = kk - rb*6;
            const int i = rep_row[rb];
            if (i >= 0) {
                int r0, r1;
                if (box == 0) { r0 = clamp05(y0a - i); r1 = clamp05(y1a - i); }
                else          { r0 = clamp05(y0b - i); r1 = clamp05(y1b - i); }
                const float* base = Pf + box*2304 + icb + g*8;
                const floatx4 p1a = *(const floatx4*)(base + (r1*6 + c)*64);
                const floatx4 p1b = *(const floatx4*)(base + (r1*6 + c)*64 + 4);
                const floatx4 p0a = *(const floatx4*)(base + (r0*6 + c)*64);
                const floatx4 p0b = *(const floatx4*)(base + (r0*6 + c)*64 + 4);
                *(floatx4*)(Qf + k*36 + g*8)     = p1a - p0a;
                *(floatx4*)(Qf + k*36 + g*8 + 4) = p1b - p0b;
            }
        }
        __syncthreads();

        // --- V-build: V[combo][ch] = Qa[c1a]-Qa[c0a]+Qb[c1b]-Qb[c0b]+b1 ---
        for (int idx = tid; idx < NCOMBO*4; idx += BLOCK) {
            const int g = idx & 3;
            const int combo = idx >> 2;
            const int rb = combo / NREG;
            const int cb = combo - rb*NREG;
            const int j = rep_col[cb];
            if (j >= 0 && rep_row[rb] >= 0) {
                const int c0a = clamp05(x0a - j), c1a = clamp05(x1a - j);
                const int c0b = clamp05(x0b - j), c1b = clamp05(x1b - j);
                const float* qa = Qf + (rb*6)*36 + g*8;
                const float* qb = Qf + (126 + rb*6)*36 + g*8;
                const floatx4 bv0 = *(const floatx4*)(b1 + icb + g*8);
                const floatx4 bv1 = *(const floatx4*)(b1 + icb + g*8 + 4);
                floatx4 v0 = *(const floatx4*)(qa + c1a*36)     - *(const floatx4*)(qa + c0a*36)
                           + *(const floatx4*)(qb + c1b*36)     - *(const floatx4*)(qb + c0b*36) + bv0;
                floatx4 v1 = *(const floatx4*)(qa + c1a*36 + 4) - *(const floatx4*)(qa + c0a*36 + 4)
                           + *(const floatx4*)(qb + c1b*36 + 4) - *(const floatx4*)(qb + c0b*36 + 4) + bv1;
                short8 o;
                #pragma unroll
                for (int e = 0; e < 4; ++e) o[e]   = (short)__bfloat16_as_ushort(__float2bfloat16(v0[e]));
                #pragma unroll
                for (int e = 0; e < 4; ++e) o[4+e] = (short)__bfloat16_as_ushort(__float2bfloat16(v1[e]));
                *(short8*)(smem + SMEM_V + (combo*32 + g*8)*2) = o;
            }
        }
        __syncthreads();   // V ready; Q dead

        // --- pool-build: pool1[cell][ch] = max of <=4 V combos (8ch/item) ---
        for (int idx = tid; idx < 3600; idx += BLOCK) {
            const int g = idx & 3;
            const int cell = idx >> 2;
            const int pi = cell / 30;
            const int pj = cell - pi*30;
            const int rb0 = band_row[2*pi], rb1 = band_row[2*pi + 1];
            const int cb0 = band_col[2*pj], cb1 = band_col[2*pj + 1];
            const uint4v u00 = *(const uint4v*)(smem + SMEM_V + ((rb0*NREG + cb0)*32 + g*8)*2);
            const uint4v u01 = *(const uint4v*)(smem + SMEM_V + ((rb0*NREG + cb1)*32 + g*8)*2);
            const uint4v u10 = *(const uint4v*)(smem + SMEM_V + ((rb1*NREG + cb0)*32 + g*8)*2);
            const uint4v u11 = *(const uint4v*)(smem + SMEM_V + ((rb1*NREG + cb1)*32 + g*8)*2);
            uint4v o;
            #pragma unroll
            for (int u = 0; u < 4; ++u) {
                const float l0 = __uint_as_float(u00[u] << 16), h0 = __uint_as_float(u00[u] & 0xffff0000u);
                const float l1 = __uint_as_float(u01[u] << 16), h1 = __uint_as_float(u01[u] & 0xffff0000u);
                const float l2 = __uint_as_float(u10[u] << 16), h2 = __uint_as_float(u10[u] & 0xffff0000u);
                const float l3 = __uint_as_float(u11[u] << 16), h3 = __uint_as_float(u11[u] & 0xffff0000u);
                const float ml = fmaxf(fmaxf(l0, l1), fmaxf(l2, l3));
                const float mh = fmaxf(fmaxf(h0, h1), fmaxf(h2, h3));
                o[u] = (__float_as_uint(ml) >> 16) | (__float_as_uint(mh) & 0xffff0000u);
            }
            *(uint4v*)(smem + SMEM_POOL + (cell*32 + g*8)*2) = o;
        }

        // --- w2s write (R region; Q dead, V no longer needed after pool-build... 
        //     pool-build reads V, w2s writes R — disjoint regions, same phase OK) ---
        #pragma unroll
        for (int p = 0; p < 25; ++p)
            w2s[p*1024 + ocl*32 + chl] = __float2bfloat16(w2reg[p]);
        __syncthreads();   // pool1 + w2s ready

        // --- MFMA: 8 waves, 6 M-tiles each, 25 taps, K=32 ---
        if (wid < 8) {
            #pragma unroll
            for (int tap = 0; tap < 25; ++tap) {
                const int toffA = ((tap/5)*30 + (tap%5))*64;
                const int toffB = tap*2048;
                const short8 bf0 = *(const short8*)(smem + bbase + toffB);
                const short8 bf1 = *(const short8*)(smem + bbase + toffB + 1024);
                #pragma unroll
                for (int s = 0; s < 6; ++s) {
                    if (wid + 8*s < 43) {
                        const short8 af = *(const short8*)(smem + abase[s] + toffA);
                        acc[s][0] = __builtin_amdgcn_mfma_f32_16x16x32_bf16(af, bf0, acc[s][0], 0, 0, 0);
                        acc[s][1] = __builtin_amdgcn_mfma_f32_16x16x32_bf16(af, bf1, acc[s][1], 0, 0, 0);
                    }
                }
            }
        }
        __syncthreads();   // drain before next chunk overwrites LDS
    }

    // --- epilogue: C (col=lane&15, row=(lane>>4)*4+reg) -> c2out[m][oc] ---
    __hip_bfloat16* c2out = (__hip_bfloat16*)(smem + SMEM_POOL);
    if (tid < 32) feat[tid] = 0.f;
    if (wid < 8) {
        const float b2v0 = b2[lr];
        const float b2v1 = b2[16 + lr];
        #pragma unroll
        for (int s = 0; s < 6; ++s) {
            const int mt = wid + 8*s;
            if (mt < 43) {
                #pragma unroll
                for (int r = 0; r < 4; ++r) {
                    const int m = mt*16 + kg*4 + r;
                    if (m < 676) {
                        c2out[m*32 + lr]      = __float2bfloat16(acc[s][0][r] + b2v0);
                        c2out[m*32 + 16 + lr] = __float2bfloat16(acc[s][1][r] + b2v1);
                    }
                }
            }
        }
    }
    __syncthreads();

    // --- pool2 2x2 + mean(13x13) ---
    {
        const int oc  = tid & 31;
        const int grp = tid >> 5;
        float sum = 0.f;
        for (int cell = grp; cell < 169; cell += 32) {
            const int ci = cell / 13;
            const int cj = cell - ci*13;
            const __hip_bfloat16* q = c2out + ((ci*2)*26 + cj*2)*32 + oc;
            const float v0 = __bfloat162float(q[0]);
            const float v1 = __bfloat162float(q[32]);
            const float v2 = __bfloat162float(q[26*32]);
            const float v3 = __bfloat162float(q[27*32]);
            sum += fmaxf(fmaxf(v0, v1), fmaxf(v2, v3));
        }
        atomicAdd(&feat[oc], sum * (1.0f/169.0f));
    }
    __syncthreads();

    // --- linear 32 -> 512 + ReLU ---
    if (tid < 512) {
        float s = bl[tid];
        #pragma unroll
        for (int ic = 0; ic < 32; ++ic)
            s = fmaf(feat[ic], Wl[ic*512 + tid], s);
        out[(size_t)t*512 + tid] = fmaxf(s, 0.f);
    }
}

extern "C" void kernel_launch(void* const* d_in, const int* in_sizes, int n_in,
                              void* d_out, int out_size, void* d_ws, size_t ws_size,
                              hipStream_t stream) {
    const float* bboxes    = (const float*)d_in[0];
    const int*   obj_pairs = (const int*)d_in[1];
    const int*   fw        = (const int*)d_in[3];
    const int*   fh        = (const int*)d_in[4];
    const float* W1        = (const float*)d_in[5];
    const float* b1        = (const float*)d_in[6];
    const float* W2        = (const float*)d_in[7];
    const float* b2        = (const float*)d_in[8];
    const float* Wl        = (const float*)d_in[9];
    const float* bl        = (const float*)d_in[10];
    float* out = (float*)d_out;

    hipFuncSetAttribute((const void*)vsgnet_mfma_kernel,
                        hipFuncAttributeMaxDynamicSharedMemorySize, SMEM_TOTAL);
    vsgnet_mfma_kernel<<<dim3(1024), dim3(BLOCK), SMEM_TOTAL, stream>>>(
        bboxes, obj_pairs, fw, fh, W1, b1, W2, b2, Wl, bl, out);
}